// Round 13
// baseline (1573.775 us; speedup 1.0000x reference)
//
#include <hip/hip_runtime.h>
#include <hip/hip_bf16.h>
#include <stdint.h>

#define NN 50000
#define NE 1600000
#define NG 64
#define FIN 256
#define HD 1024
#define EPSV 1e-5f

typedef __bf16 bf16;
typedef float f32x4 __attribute__((ext_vector_type(4)));
typedef int i32x4 __attribute__((ext_vector_type(4)));

typedef const __attribute__((address_space(1))) void* gptr_as1;
typedef __attribute__((address_space(3))) void* lptr_as3;

__device__ __forceinline__ void load_g2l_16(const void* g, const void* l) {
  __builtin_amdgcn_global_load_lds((gptr_as1)(uintptr_t)g,
                                   (lptr_as3)(uint32_t)(uintptr_t)l, 16, 0, 0);
}

// ---------------- degree histogram ----------------
__global__ void hist_kernel(const int* __restrict__ col, int* __restrict__ cnt, int E) {
  int e = blockIdx.x * 256 + threadIdx.x;
  if (e < E) atomicAdd(&cnt[col[e]], 1);
}

// ---------------- exclusive scan (3-phase); final also emits dinv ----------------
__global__ void scan_partial_kernel(const int* __restrict__ cnt, int* __restrict__ partial, int n) {
  __shared__ int red[4];
  int i = blockIdx.x * 256 + threadIdx.x;
  int v = (i < n) ? cnt[i] : 0;
  #pragma unroll
  for (int off = 32; off; off >>= 1) v += __shfl_down(v, off, 64);
  if ((threadIdx.x & 63) == 0) red[threadIdx.x >> 6] = v;
  __syncthreads();
  if (threadIdx.x == 0) partial[blockIdx.x] = red[0] + red[1] + red[2] + red[3];
}

__global__ void scan_scan_kernel(int* __restrict__ partial, int nb) {
  __shared__ int s[256];
  int t = threadIdx.x;
  int v = (t < nb) ? partial[t] : 0;
  s[t] = v;
  __syncthreads();
  for (int off = 1; off < 256; off <<= 1) {
    int x = (t >= off) ? s[t - off] : 0;
    __syncthreads();
    s[t] += x;
    __syncthreads();
  }
  if (t < nb) partial[t] = s[t] - v;  // exclusive
}

__global__ void scan_final_kernel(const int* __restrict__ cnt, const int* __restrict__ partial,
                                  int* __restrict__ row_ptr, float* __restrict__ dinv,
                                  int n, int E) {
  __shared__ int s[256];
  int t = threadIdx.x;
  int i = blockIdx.x * 256 + t;
  int v = (i < n) ? cnt[i] : 0;
  s[t] = v;
  __syncthreads();
  for (int off = 1; off < 256; off <<= 1) {
    int x = (t >= off) ? s[t - off] : 0;
    __syncthreads();
    s[t] += x;
    __syncthreads();
  }
  if (i < n) {
    row_ptr[i] = partial[blockIdx.x] + s[t] - v;
    dinv[i] = rsqrtf((float)(v + 1));   // +1 self-loop
  }
  if (i == 0) row_ptr[n] = E;
}

// ---------------- CSR scatter (packed {src, w_bits}) ----------------
__global__ void scatter_kernel(const int* __restrict__ rowi, const int* __restrict__ coli,
                               const int* __restrict__ row_ptr, int* __restrict__ fill,
                               const float* __restrict__ dinv,
                               int2* __restrict__ csr_sw, int E) {
  int e = blockIdx.x * 256 + threadIdx.x;
  if (e >= E) return;
  int s = rowi[e], d = coli[e];
  int pos = row_ptr[d] + atomicAdd(&fill[d], 1);
  int2 p;
  p.x = s;
  p.y = __float_as_int(dinv[s] * dinv[d]);
  csr_sw[pos] = p;
}

// ---------------- x f32 -> per-row biased u8 (for agg0 gather) ----------------
__global__ __launch_bounds__(256) void quant_x_kernel(const float* __restrict__ x,
                                                      uint8_t* __restrict__ X8,
                                                      float* __restrict__ xscale) {
  int row = blockIdx.x * 4 + (threadIdx.x >> 6);
  int t = threadIdx.x & 63;
  float4 v = ((const float4*)(x + (size_t)row * FIN))[t];
  float m = fmaxf(fmaxf(fabsf(v.x), fabsf(v.y)), fmaxf(fabsf(v.z), fabsf(v.w)));
  #pragma unroll
  for (int off = 32; off; off >>= 1) m = fmaxf(m, __shfl_xor(m, off, 64));
  float inv = (m > 0.f) ? 127.0f / m : 0.f;
  int q0 = min(127, max(-127, __float2int_rn(v.x * inv))) + 128;
  int q1 = min(127, max(-127, __float2int_rn(v.y * inv))) + 128;
  int q2 = min(127, max(-127, __float2int_rn(v.z * inv))) + 128;
  int q3 = min(127, max(-127, __float2int_rn(v.w * inv))) + 128;
  uint32_t p = ((uint32_t)q0) | ((uint32_t)q1 << 8) |
               ((uint32_t)q2 << 16) | ((uint32_t)q3 << 24);
  ((uint32_t*)X8)[(size_t)row * 64 + t] = p;
  if (t == 0) xscale[row] = (m > 0.f) ? m / 127.0f : 0.f;
}

// ---------------- L0 aggregate-first: AX = A-hat * x (256-d gather) ----------------
__global__ __launch_bounds__(256) void agg0_kernel(
    const uint8_t* __restrict__ X8, const float* __restrict__ xscale,
    const int* __restrict__ row_ptr, const int2* __restrict__ csr_sw,
    const float* __restrict__ dinv,
    int8_t* __restrict__ AX8, float* __restrict__ axscale) {
  const int node = blockIdx.x * 4 + (threadIdx.x >> 6);
  const int t = threadIdx.x & 63;

  float acc[4] = {};
  float sw = 0.f;

  float dn = dinv[node];
  float wself = dn * dn * xscale[node];
  {
    uint32_t d = ((const uint32_t*)X8)[(size_t)node * 64 + t];
    sw += wself;
    acc[0] += wself * (float)(d & 0xffu);
    acc[1] += wself * (float)((d >> 8) & 0xffu);
    acc[2] += wself * (float)((d >> 16) & 0xffu);
    acc[3] += wself * (float)(d >> 24);
  }

  int e = row_ptr[node];
  const int e1 = row_ptr[node + 1];
  for (; e + 4 <= e1; e += 4) {
    int2 p0 = csr_sw[e], p1 = csr_sw[e + 1], p2 = csr_sw[e + 2], p3 = csr_sw[e + 3];
    float w0 = __int_as_float(p0.y) * xscale[p0.x];
    float w1 = __int_as_float(p1.y) * xscale[p1.x];
    float w2 = __int_as_float(p2.y) * xscale[p2.x];
    float w3 = __int_as_float(p3.y) * xscale[p3.x];
    uint32_t d0 = ((const uint32_t*)X8)[(size_t)p0.x * 64 + t];
    uint32_t d1 = ((const uint32_t*)X8)[(size_t)p1.x * 64 + t];
    uint32_t d2 = ((const uint32_t*)X8)[(size_t)p2.x * 64 + t];
    uint32_t d3 = ((const uint32_t*)X8)[(size_t)p3.x * 64 + t];
    sw += w0 + w1 + w2 + w3;
    acc[0] += w0 * (float)(d0 & 0xffu) + w1 * (float)(d1 & 0xffu)
            + w2 * (float)(d2 & 0xffu) + w3 * (float)(d3 & 0xffu);
    acc[1] += w0 * (float)((d0 >> 8) & 0xffu) + w1 * (float)((d1 >> 8) & 0xffu)
            + w2 * (float)((d2 >> 8) & 0xffu) + w3 * (float)((d3 >> 8) & 0xffu);
    acc[2] += w0 * (float)((d0 >> 16) & 0xffu) + w1 * (float)((d1 >> 16) & 0xffu)
            + w2 * (float)((d2 >> 16) & 0xffu) + w3 * (float)((d3 >> 16) & 0xffu);
    acc[3] += w0 * (float)(d0 >> 24) + w1 * (float)(d1 >> 24)
            + w2 * (float)(d2 >> 24) + w3 * (float)(d3 >> 24);
  }
  for (; e < e1; e++) {
    int2 p = csr_sw[e];
    float w = __int_as_float(p.y) * xscale[p.x];
    uint32_t d = ((const uint32_t*)X8)[(size_t)p.x * 64 + t];
    sw += w;
    acc[0] += w * (float)(d & 0xffu);
    acc[1] += w * (float)((d >> 8) & 0xffu);
    acc[2] += w * (float)((d >> 16) & 0xffu);
    acc[3] += w * (float)(d >> 24);
  }

  float c = 128.0f * sw;
  #pragma unroll
  for (int j = 0; j < 4; j++) acc[j] -= c;

  float rm = fmaxf(fmaxf(fabsf(acc[0]), fabsf(acc[1])), fmaxf(fabsf(acc[2]), fabsf(acc[3])));
  #pragma unroll
  for (int off = 32; off; off >>= 1) rm = fmaxf(rm, __shfl_xor(rm, off, 64));
  float qinv = (rm > 0.f) ? 127.0f / rm : 0.f;
  int q0 = min(127, max(-127, __float2int_rn(acc[0] * qinv)));
  int q1 = min(127, max(-127, __float2int_rn(acc[1] * qinv)));
  int q2 = min(127, max(-127, __float2int_rn(acc[2] * qinv)));
  int q3 = min(127, max(-127, __float2int_rn(acc[3] * qinv)));
  uint32_t p = ((uint32_t)(q0 & 0xff)) | ((uint32_t)(q1 & 0xff) << 8) |
               ((uint32_t)(q2 & 0xff) << 16) | ((uint32_t)(q3 & 0xff) << 24);
  ((uint32_t*)AX8)[(size_t)node * 64 + t] = p;
  if (t == 0) axscale[node] = (rm > 0.f) ? rm / 127.0f : 0.f;
}

// ---------------- XCD column-sliced aggregation (L1-3) ----------------
// chunk = blockIdx.x & 7 rides the round-robin block->XCD mapping so each
// XCD's L2 only caches a 6.4MB column slice of ht8 (vs 51MB whole array).
// 8 lanes per node cover 128 cols = exactly one 128B line per edge.
// Output: per-(node,chunk) biased u8 + scales2 -- same format as the GEMM
// epilogue, so ln0_kernel is reused as the LN pass.
__global__ __launch_bounds__(256) void agg_chunk_kernel(
    const uint8_t* __restrict__ htu8, const float* __restrict__ scales,
    const int* __restrict__ row_ptr, const int2* __restrict__ csr_sw,
    const float* __restrict__ dinv,
    uint8_t* __restrict__ agg8, float* __restrict__ scales2) {
  const int chunk = blockIdx.x & 7;
  const int node = (blockIdx.x >> 3) * 32 + (threadIdx.x >> 3);
  if (node >= NN) return;            // whole 8-lane group exits together
  const int sl = threadIdx.x & 7;    // sub-lane: cols [chunk*128+sl*16, +16)
  const int coff = chunk * 128 + sl * 16;

  float acc[16] = {};
  float sw = 0.f;

  auto ACC = [&](float w, const uint4& dd) {
    sw += w;
    const uint32_t dw[4] = {dd.x, dd.y, dd.z, dd.w};
    #pragma unroll
    for (int c = 0; c < 4; c++) {
      acc[4 * c + 0] += w * (float)(dw[c] & 0xffu);
      acc[4 * c + 1] += w * (float)((dw[c] >> 8) & 0xffu);
      acc[4 * c + 2] += w * (float)((dw[c] >> 16) & 0xffu);
      acc[4 * c + 3] += w * (float)(dw[c] >> 24);
    }
  };

  // self-loop
  float dn = dinv[node];
  float wself = dn * dn * scales[(size_t)node * 8 + chunk];
  ACC(wself, *(const uint4*)(htu8 + (size_t)node * HD + coff));

  int e = row_ptr[node];
  const int e1 = row_ptr[node + 1];
  for (; e + 4 <= e1; e += 4) {
    int2 p0 = csr_sw[e], p1 = csr_sw[e + 1], p2 = csr_sw[e + 2], p3 = csr_sw[e + 3];
    float w0 = __int_as_float(p0.y) * scales[(size_t)p0.x * 8 + chunk];
    float w1 = __int_as_float(p1.y) * scales[(size_t)p1.x * 8 + chunk];
    float w2 = __int_as_float(p2.y) * scales[(size_t)p2.x * 8 + chunk];
    float w3 = __int_as_float(p3.y) * scales[(size_t)p3.x * 8 + chunk];
    uint4 d0 = *(const uint4*)(htu8 + (size_t)p0.x * HD + coff);
    uint4 d1 = *(const uint4*)(htu8 + (size_t)p1.x * HD + coff);
    uint4 d2 = *(const uint4*)(htu8 + (size_t)p2.x * HD + coff);
    uint4 d3 = *(const uint4*)(htu8 + (size_t)p3.x * HD + coff);
    ACC(w0, d0);
    ACC(w1, d1);
    ACC(w2, d2);
    ACC(w3, d3);
  }
  for (; e < e1; e++) {
    int2 p = csr_sw[e];
    float wgt = __int_as_float(p.y) * scales[(size_t)p.x * 8 + chunk];
    ACC(wgt, *(const uint4*)(htu8 + (size_t)p.x * HD + coff));
  }

  // remove the +128 gather bias
  float c128 = 128.0f * sw;
  #pragma unroll
  for (int j = 0; j < 16; j++) acc[j] -= c128;

  // per-(node,chunk) amax over the 8 sub-lanes (group-local xor shuffles)
  float rm = 0.f;
  #pragma unroll
  for (int j = 0; j < 16; j++) rm = fmaxf(rm, fabsf(acc[j]));
  rm = fmaxf(rm, __shfl_xor(rm, 1, 64));
  rm = fmaxf(rm, __shfl_xor(rm, 2, 64));
  rm = fmaxf(rm, __shfl_xor(rm, 4, 64));
  float qinv = (rm > 0.f) ? 127.0f / rm : 0.f;

  uint32_t pw[4];
  #pragma unroll
  for (int c = 0; c < 4; c++) {
    int q0 = min(127, max(-127, __float2int_rn(acc[4 * c + 0] * qinv))) + 128;
    int q1 = min(127, max(-127, __float2int_rn(acc[4 * c + 1] * qinv))) + 128;
    int q2 = min(127, max(-127, __float2int_rn(acc[4 * c + 2] * qinv))) + 128;
    int q3 = min(127, max(-127, __float2int_rn(acc[4 * c + 3] * qinv))) + 128;
    pw[c] = ((uint32_t)q0) | ((uint32_t)q1 << 8) | ((uint32_t)q2 << 16) | ((uint32_t)q3 << 24);
  }
  uint4 pk; pk.x = pw[0]; pk.y = pw[1]; pk.z = pw[2]; pk.w = pw[3];
  *(uint4*)(agg8 + (size_t)node * HD + coff) = pk;
  if (sl == 0) scales2[(size_t)node * 8 + chunk] = (rm > 0.f) ? rm / 127.0f : 0.f;
}

// ---------------- dequant + bias + LayerNorm + ReLU + i8 quant ----------------
// Input: per-(node,128-col-block)-scaled biased u8 (GEMM epilogue or agg_chunk).
__global__ __launch_bounds__(256) void ln0_kernel(
    const uint8_t* __restrict__ htu8, const float* __restrict__ scales,
    const float* __restrict__ bias, const float* __restrict__ gamma,
    const float* __restrict__ beta,
    int8_t* __restrict__ hq, float* __restrict__ hscale) {
  const int g = threadIdx.x >> 7;
  const int node = blockIdx.x * 2 + g;
  const int tt = threadIdx.x & 127;
  const int cbL = tt >> 4;
  const int wid = threadIdx.x >> 6;
  __shared__ float red[4];

  float sc = scales[(size_t)node * 8 + cbL];
  uint2 dd = ((const uint2*)(htu8 + (size_t)node * HD))[tt];
  float acc[8];
  acc[0] = sc * ((float)(dd.x & 0xffu) - 128.f);
  acc[1] = sc * ((float)((dd.x >> 8) & 0xffu) - 128.f);
  acc[2] = sc * ((float)((dd.x >> 16) & 0xffu) - 128.f);
  acc[3] = sc * ((float)(dd.x >> 24) - 128.f);
  acc[4] = sc * ((float)(dd.y & 0xffu) - 128.f);
  acc[5] = sc * ((float)((dd.y >> 8) & 0xffu) - 128.f);
  acc[6] = sc * ((float)((dd.y >> 16) & 0xffu) - 128.f);
  acc[7] = sc * ((float)(dd.y >> 24) - 128.f);

  const float4* bias2 = (const float4*)bias;
  float4 ba = bias2[tt * 2], bb = bias2[tt * 2 + 1];
  acc[0] += ba.x; acc[1] += ba.y; acc[2] += ba.z; acc[3] += ba.w;
  acc[4] += bb.x; acc[5] += bb.y; acc[6] += bb.z; acc[7] += bb.w;

  float s = 0.f;
  #pragma unroll
  for (int j = 0; j < 8; j++) s += acc[j];
  #pragma unroll
  for (int off = 32; off; off >>= 1) s += __shfl_down(s, off, 64);
  if ((threadIdx.x & 63) == 0) red[wid] = s;
  __syncthreads();
  float mean = (red[g * 2] + red[g * 2 + 1]) * (1.0f / HD);
  __syncthreads();

  float d[8], s2 = 0.f;
  #pragma unroll
  for (int j = 0; j < 8; j++) { d[j] = acc[j] - mean; s2 += d[j] * d[j]; }
  #pragma unroll
  for (int off = 32; off; off >>= 1) s2 += __shfl_down(s2, off, 64);
  if ((threadIdx.x & 63) == 0) red[wid] = s2;
  __syncthreads();
  float var = (red[g * 2] + red[g * 2 + 1]) * (1.0f / HD);
  float rstd = rsqrtf(var + EPSV);

  const float4* gam2 = (const float4*)gamma;
  const float4* bet2 = (const float4*)beta;
  float4 g0 = gam2[tt * 2], g1 = gam2[tt * 2 + 1];
  float4 be0 = bet2[tt * 2], be1 = bet2[tt * 2 + 1];
  float gv[8] = {g0.x, g0.y, g0.z, g0.w, g1.x, g1.y, g1.z, g1.w};
  float bv[8] = {be0.x, be0.y, be0.z, be0.w, be1.x, be1.y, be1.z, be1.w};
  float o[8];
  float rmax = 0.f;
  #pragma unroll
  for (int j = 0; j < 8; j++) {
    o[j] = fmaxf(d[j] * rstd * gv[j] + bv[j], 0.0f);
    rmax = fmaxf(rmax, o[j]);
  }

  __syncthreads();
  #pragma unroll
  for (int off = 32; off; off >>= 1) rmax = fmaxf(rmax, __shfl_xor(rmax, off, 64));
  if ((threadIdx.x & 63) == 0) red[wid] = rmax;
  __syncthreads();
  float rm = fmaxf(red[g * 2], red[g * 2 + 1]);
  float qinv = (rm > 0.f) ? 127.0f / rm : 0.f;
  int q[8];
  #pragma unroll
  for (int j = 0; j < 8; j++) q[j] = min(127, __float2int_rn(o[j] * qinv));
  uint32_t p0 = ((uint32_t)q[0]) | ((uint32_t)q[1] << 8) | ((uint32_t)q[2] << 16) | ((uint32_t)q[3] << 24);
  uint32_t p1 = ((uint32_t)q[4]) | ((uint32_t)q[5] << 8) | ((uint32_t)q[6] << 16) | ((uint32_t)q[7] << 24);
  uint2 pk; pk.x = p0; pk.y = p1;
  ((uint2*)(hq + (size_t)node * HD))[tt] = pk;
  if (tt == 0) hscale[node] = (rm > 0.f) ? rm / 127.0f : 0.f;
}

// ---------------- batched weight prep (all 4 layers, hoisted) ----------------
__device__ __forceinline__ const float* layer_W(const float* W0, const float* Ws, int L) {
  return (L == 0) ? W0 : Ws + (size_t)(L - 1) * HD * HD;
}

__global__ void wamax_full_kernel(const float* __restrict__ W0, const float* __restrict__ Ws,
                                  float* __restrict__ colmaxf, float* __restrict__ wscale) {
  __shared__ float lds[8][32];
  int L = blockIdx.y;
  int K = (L == 0) ? FIN : HD;
  const float* W = layer_W(W0, Ws, L);
  int n = blockIdx.x * 32 + threadIdx.x;
  float m = 0.f;
  for (int k = threadIdx.y; k < K; k += 8)
    m = fmaxf(m, fabsf(W[(size_t)k * HD + n]));
  lds[threadIdx.y][threadIdx.x] = m;
  __syncthreads();
  if (threadIdx.y == 0) {
    #pragma unroll
    for (int i = 1; i < 8; i++) m = fmaxf(m, lds[i][threadIdx.x]);
    colmaxf[L * HD + n] = m;
    wscale[L * HD + n] = (m > 0.f) ? m / 127.0f : 0.f;
  }
}

// Wt8_all layout: L0 at off 0 (HD rows x 256), L1.. at FIN*HD + (L-1)*HD*HD
__global__ void transpose_wq8_all_kernel(const float* __restrict__ W0,
                                         const float* __restrict__ Ws,
                                         const float* __restrict__ colmaxf,
                                         int8_t* __restrict__ Wt8_all) {
  __shared__ float tile[32][33];
  int L = blockIdx.z;
  int K = (L == 0) ? FIN : HD;
  int k0 = blockIdx.y * 32;
  if (k0 >= K) return;
  const float* W = layer_W(W0, Ws, L);
  int8_t* Wt8 = Wt8_all + ((L == 0) ? 0 : (size_t)FIN * HD + (size_t)(L - 1) * HD * HD);
  int n0 = blockIdx.x * 32;
  int tx = threadIdx.x, ty = threadIdx.y;  // 32 x 8
  #pragma unroll
  for (int i = ty; i < 32; i += 8) tile[i][tx] = W[(size_t)(k0 + i) * HD + n0 + tx];
  __syncthreads();
  #pragma unroll
  for (int i = ty; i < 32; i += 8) {
    float cm = colmaxf[L * HD + n0 + i];
    float inv = (cm > 0.f) ? 127.0f / cm : 0.f;
    int q = min(127, max(-127, __float2int_rn(tile[tx][i] * inv)));
    Wt8[(size_t)(n0 + i) * K + k0 + tx] = (int8_t)q;
  }
}

// ---------------- i8 MFMA GEMM + fused u8-quant epilogue ----------------
__global__ __launch_bounds__(256, 4) void gemm_i8_q8_kernel(
    const int8_t* __restrict__ A8, const float* __restrict__ hscale,
    const int8_t* __restrict__ Wt8, const float* __restrict__ wscale,
    uint8_t* __restrict__ C8, float* __restrict__ scales, int M, int K) {
  __shared__ __align__(16) int8_t As[2][128 * 64];
  __shared__ __align__(16) int8_t Bs[2][128 * 64];
  __shared__ float smax[2][128];
  const int tid = threadIdx.x;
  const int w = tid >> 6, l = tid & 63;

  const int nwg = gridDim.x;            // nmt*8, divisible by 8
  const int o = blockIdx.x;
  const int lid = (o & 7) * (nwg >> 3) + (o >> 3);
  const int m0 = (lid >> 3) * 128, n0 = (lid & 7) * 128;
  const int cb = lid & 7;               // col-block id
  const int wr = w >> 1, wc = w & 1;    // 2x2 wave grid, each wave 64x64

  i32x4 acc[4][4] = {};

  const int r0 = tid >> 2;              // 0..63
  const int c16 = (tid & 3) * 16;       // byte offset within BK=64 row
  int ar0 = m0 + r0;       if (ar0 >= M) ar0 = M - 1;
  int ar1 = m0 + r0 + 64;  if (ar1 >= M) ar1 = M - 1;
  const int8_t* a0 = A8 + (size_t)ar0 * K + c16;
  const int8_t* a1 = A8 + (size_t)ar1 * K + c16;
  const int8_t* b0 = Wt8 + (size_t)(n0 + r0) * K + c16;
  const int8_t* b1 = Wt8 + (size_t)(n0 + r0 + 64) * K + c16;

  const int mrow = l & 15;
  const int kch = (l >> 4) * 16;        // byte offset within row

  auto stage = [&](int b, int k) {
    int8_t* asw = &As[b][w * 1024];
    int8_t* bsw = &Bs[b][w * 1024];
    load_g2l_16(a0 + k, asw);
    load_g2l_16(a1 + k, asw + 4096);
    load_g2l_16(b0 + k, bsw);
    load_g2l_16(b1 + k, bsw + 4096);
  };

  const int nit = K >> 6;
  stage(0, 0);
  __syncthreads();

  int cur = 0;
  for (int t = 0; t < nit; ++t) {
    if (t + 1 < nit) stage(cur ^ 1, (t + 1) << 6);
    i32x4 af[4], bf_[4];
    #pragma unroll
    for (int m = 0; m < 4; m++)
      af[m] = *(const i32x4*)&As[cur][(wr * 64 + m * 16 + mrow) * 64 + kch];
    #pragma unroll
    for (int n = 0; n < 4; n++)
      bf_[n] = *(const i32x4*)&Bs[cur][(wc * 64 + n * 16 + mrow) * 64 + kch];
    #pragma unroll
    for (int m = 0; m < 4; m++)
      #pragma unroll
      for (int n = 0; n < 4; n++)
        acc[m][n] = __builtin_amdgcn_mfma_i32_16x16x64_i8(af[m], bf_[n], acc[m][n], 0, 0, 0);
    __syncthreads();
    cur ^= 1;
  }

  // ---- epilogue: per-row amax over this block's 128 cols, then quant ----
  float wsv[4];
  #pragma unroll
  for (int n = 0; n < 4; n++) wsv[n] = wscale[n0 + wc * 64 + n * 16 + (l & 15)];

  #pragma unroll
  for (int m = 0; m < 4; m++) {
    #pragma unroll
    for (int r = 0; r < 4; r++) {
      int rl = wr * 64 + m * 16 + (l >> 4) * 4 + r;
      int grow = m0 + rl; if (grow >= M) grow = M - 1;
      float v = 0.f;
      #pragma unroll
      for (int n = 0; n < 4; n++)
        v = fmaxf(v, fabsf((float)acc[m][n][r] * wsv[n]));
      v *= hscale[grow];   // hs >= 0: factor out of the max
      #pragma unroll
      for (int mask = 1; mask < 16; mask <<= 1) v = fmaxf(v, __shfl_xor(v, mask, 64));
      if ((l & 15) == 0) smax[wc][rl] = v;
    }
  }
  __syncthreads();

  #pragma unroll
  for (int m = 0; m < 4; m++) {
    #pragma unroll
    for (int r = 0; r < 4; r++) {
      int rl = wr * 64 + m * 16 + (l >> 4) * 4 + r;
      int grow = m0 + rl;
      float mx = fmaxf(smax[0][rl], smax[1][rl]);
      float inv = (mx > 0.f) ? 127.0f / mx : 0.f;
      if (grow < M) {
        float hs = hscale[grow];
        if (wc == 0 && (l & 15) == 0)
          scales[(size_t)grow * 8 + cb] = (mx > 0.f) ? mx / 127.0f : 0.f;
        #pragma unroll
        for (int n = 0; n < 4; n++) {
          int gcol = n0 + wc * 64 + n * 16 + (l & 15);
          int u = __float2int_rn((float)acc[m][n][r] * hs * wsv[n] * inv) + 128;
          C8[(size_t)grow * HD + gcol] = (uint8_t)u;
        }
      }
    }
  }
}

// ---------------- graph boundaries (batch is sorted) ----------------
__global__ void starts_kernel(const int* __restrict__ batch, int* __restrict__ start,
                              int n, int ngraph) {
  int g = blockIdx.x * blockDim.x + threadIdx.x;
  if (g > ngraph) return;
  int lo = 0, hi = n;
  while (lo < hi) {
    int mid = (lo + hi) >> 1;
    if (batch[mid] < g) lo = mid + 1; else hi = mid;
  }
  start[g] = lo;
}

// ---------------- mean-pool per graph (i8 input): partial sums + atomics ----------------
#define POOL_CHUNKS 8
__global__ void pool_partial_kernel(const int8_t* __restrict__ hq,
                                    const float* __restrict__ hscale,
                                    const int* __restrict__ start,
                                    float* __restrict__ out) {
  int g = blockIdx.y, c = blockIdx.x;
  int t = threadIdx.x;
  int s0 = start[g], s1 = start[g + 1];
  int len = s1 - s0;
  int per = (len + POOL_CHUNKS - 1) / POOL_CHUNKS;
  int a = s0 + c * per;
  int b = min(a + per, s1);
  if (a >= b) return;
  f32x4 acc = {0.f, 0.f, 0.f, 0.f};
  for (int n = a; n < b; n++) {
    float hs = hscale[n];
    uint32_t d = ((const uint32_t*)(hq + (size_t)n * HD))[t];   // 4 vals, 0..127
    acc[0] += hs * (float)(d & 0xffu);
    acc[1] += hs * (float)((d >> 8) & 0xffu);
    acc[2] += hs * (float)((d >> 16) & 0xffu);
    acc[3] += hs * (float)(d >> 24);
  }
  float* o = out + (size_t)g * HD + t * 4;
  atomicAdd(o + 0, acc[0]);
  atomicAdd(o + 1, acc[1]);
  atomicAdd(o + 2, acc[2]);
  atomicAdd(o + 3, acc[3]);
}

__global__ void pool_div_kernel(float* __restrict__ out, const int* __restrict__ start) {
  int i = blockIdx.x * 256 + threadIdx.x;
  if (i >= NG * HD) return;
  int g = i >> 10;
  float c = (float)max(start[g + 1] - start[g], 1);
  out[i] = out[i] / c;
}

extern "C" void kernel_launch(void* const* d_in, const int* in_sizes, int n_in,
                              void* d_out, int out_size, void* d_ws, size_t ws_size,
                              hipStream_t stream) {
  const float* x      = (const float*)d_in[0];
  const int*   eidx   = (const int*)d_in[1];
  const int*   batch  = (const int*)d_in[2];
  const float* W0     = (const float*)d_in[3];
  const float* b0     = (const float*)d_in[4];
  const float* Ws     = (const float*)d_in[5];
  const float* bs     = (const float*)d_in[6];
  const float* gammas = (const float*)d_in[7];
  const float* betas  = (const float*)d_in[8];
  float* out = (float*)d_out;

  const int* erow = eidx;        // sources
  const int* ecol = eidx + NE;   // targets (aggregation index)

  char* ws = (char*)d_ws;
  size_t off = 0;
  auto alloc = [&](size_t bytes) {
    void* p = ws + off;
    off = (off + bytes + 255) & ~(size_t)255;
    return p;
  };
  int*     cnt     = (int*)alloc((size_t)NN * 4);      // later: wscale[4K] + colmaxf[4K]
  int*     row_ptr = (int*)alloc((size_t)(NN + 1) * 4);
  int*     fill    = (int*)alloc((size_t)NN * 4);      // later: hscale (NN floats)
  int*     partial = (int*)alloc(256 * 4);
  float*   dinv    = (float*)alloc((size_t)NN * 4);
  int2*    csr_sw  = (int2*)alloc((size_t)NE * 8);
  int8_t*  Wt8     = (int8_t*)alloc((size_t)FIN * HD + 3 * (size_t)HD * HD);
  int8_t*  A8      = (int8_t*)alloc((size_t)NN * HD);  // i8 activations
  uint8_t* ht8     = (uint8_t*)alloc((size_t)NN * HD); // u8 GEMM output
  float*   scales  = (float*)alloc((size_t)NN * 8 * 4);
  uint8_t* agg8    = (uint8_t*)alloc((size_t)NN * HD); // u8 aggregate (pre-LN)
  float*   scales2 = (float*)alloc((size_t)NN * 8 * 4);
  uint8_t* X8      = (uint8_t*)alloc((size_t)NN * FIN); // biased-u8 x (L0 gather)
  int8_t*  AX8     = (int8_t*)alloc((size_t)NN * FIN);  // i8 aggregated x (GEMM0 input)
  float*   xscale  = (float*)alloc((size_t)NN * 4);
  float*   axscale = (float*)alloc((size_t)NN * 4);
  int*     gstart  = (int*)alloc(65 * 4);

  float* wscale  = (float*)cnt;                 // cnt dead after scans
  float* colmaxf = (float*)cnt + 4096;
  float* hscale  = (float*)fill;                // fill dead after scatter

  hipMemsetAsync(cnt, 0, (size_t)NN * 4, stream);
  hipMemsetAsync(fill, 0, (size_t)NN * 4, stream);
  hipMemsetAsync(out, 0, (size_t)NG * HD * 4, stream);

  hist_kernel<<<(NE + 255) / 256, 256, 0, stream>>>(ecol, cnt, NE);
  int nb = (NN + 255) / 256;  // 196
  scan_partial_kernel<<<nb, 256, 0, stream>>>(cnt, partial, NN);
  scan_scan_kernel<<<1, 256, 0, stream>>>(partial, nb);
  scan_final_kernel<<<nb, 256, 0, stream>>>(cnt, partial, row_ptr, dinv, NN, NE);
  scatter_kernel<<<(NE + 255) / 256, 256, 0, stream>>>(erow, ecol, row_ptr, fill, dinv,
                                                       csr_sw, NE);
  starts_kernel<<<1, 128, 0, stream>>>(batch, gstart, NN, NG);

  // x -> biased u8 (for agg0's gather)
  quant_x_kernel<<<NN / 4, 256, 0, stream>>>(x, X8, xscale);

  // batched weight prep for all 4 layers (cnt region dead after scans)
  wamax_full_kernel<<<dim3(HD / 32, 4), dim3(32, 8), 0, stream>>>(W0, Ws, colmaxf, wscale);
  transpose_wq8_all_kernel<<<dim3(HD / 32, HD / 32, 4), dim3(32, 8), 0, stream>>>(
      W0, Ws, colmaxf, Wt8);

  const int nmt = (NN + 127) / 128;  // 391 m-tiles
  const int nagg = ((NN + 31) / 32) * 8;  // agg_chunk grid (divisible by 8)

  // ---- L0: aggregate-first (A-hat x is a 256-d gather: 4x fewer bytes) ----
  agg0_kernel<<<NN / 4, 256, 0, stream>>>(X8, xscale, row_ptr, csr_sw, dinv, AX8, axscale);
  gemm_i8_q8_kernel<<<nmt * 8, 256, 0, stream>>>(AX8, axscale, Wt8, wscale,
                                                 ht8, scales, NN, FIN);
  ln0_kernel<<<NN / 2, 256, 0, stream>>>(ht8, scales, b0, gammas, betas, A8, hscale);

  // ---- L1-3: GEMM -> XCD column-sliced aggregate -> LN ----
  for (int L = 1; L < 4; L++) {
    const int8_t* WtL = Wt8 + (size_t)FIN * HD + (size_t)(L - 1) * HD * HD;
    const float* bias = bs + (size_t)(L - 1) * HD;
    gemm_i8_q8_kernel<<<nmt * 8, 256, 0, stream>>>(A8, hscale, WtL, wscale + L * HD,
                                                   ht8, scales, NN, HD);
    agg_chunk_kernel<<<nagg, 256, 0, stream>>>(ht8, scales, row_ptr, csr_sw, dinv,
                                               agg8, scales2);
    ln0_kernel<<<NN / 2, 256, 0, stream>>>(agg8, scales2, bias, gammas + (size_t)L * HD,
                                           betas + (size_t)L * HD, A8, hscale);
  }

  pool_partial_kernel<<<dim3(POOL_CHUNKS, NG), 256, 0, stream>>>(A8, hscale, gstart, out);
  pool_div_kernel<<<(NG * HD + 255) / 256, 256, 0, stream>>>(out, gstart);
}

// Round 14
// 1410.436 us; speedup vs baseline: 1.1158x; 1.1158x over previous
//
#include <hip/hip_runtime.h>
#include <hip/hip_bf16.h>
#include <stdint.h>

#define NN 50000
#define NE 1600000
#define NG 64
#define FIN 256
#define HD 1024
#define EPSV 1e-5f

typedef __bf16 bf16;
typedef float f32x4 __attribute__((ext_vector_type(4)));
typedef int i32x4 __attribute__((ext_vector_type(4)));

typedef const __attribute__((address_space(1))) void* gptr_as1;
typedef __attribute__((address_space(3))) void* lptr_as3;

__device__ __forceinline__ void load_g2l_16(const void* g, const void* l) {
  __builtin_amdgcn_global_load_lds((gptr_as1)(uintptr_t)g,
                                   (lptr_as3)(uint32_t)(uintptr_t)l, 16, 0, 0);
}

// ---------------- degree histogram ----------------
__global__ void hist_kernel(const int* __restrict__ col, int* __restrict__ cnt, int E) {
  int e = blockIdx.x * 256 + threadIdx.x;
  if (e < E) atomicAdd(&cnt[col[e]], 1);
}

// ---------------- exclusive scan (3-phase); final also emits dinv ----------------
__global__ void scan_partial_kernel(const int* __restrict__ cnt, int* __restrict__ partial, int n) {
  __shared__ int red[4];
  int i = blockIdx.x * 256 + threadIdx.x;
  int v = (i < n) ? cnt[i] : 0;
  #pragma unroll
  for (int off = 32; off; off >>= 1) v += __shfl_down(v, off, 64);
  if ((threadIdx.x & 63) == 0) red[threadIdx.x >> 6] = v;
  __syncthreads();
  if (threadIdx.x == 0) partial[blockIdx.x] = red[0] + red[1] + red[2] + red[3];
}

__global__ void scan_scan_kernel(int* __restrict__ partial, int nb) {
  __shared__ int s[256];
  int t = threadIdx.x;
  int v = (t < nb) ? partial[t] : 0;
  s[t] = v;
  __syncthreads();
  for (int off = 1; off < 256; off <<= 1) {
    int x = (t >= off) ? s[t - off] : 0;
    __syncthreads();
    s[t] += x;
    __syncthreads();
  }
  if (t < nb) partial[t] = s[t] - v;  // exclusive
}

__global__ void scan_final_kernel(const int* __restrict__ cnt, const int* __restrict__ partial,
                                  int* __restrict__ row_ptr, float* __restrict__ dinv,
                                  int n, int E) {
  __shared__ int s[256];
  int t = threadIdx.x;
  int i = blockIdx.x * 256 + t;
  int v = (i < n) ? cnt[i] : 0;
  s[t] = v;
  __syncthreads();
  for (int off = 1; off < 256; off <<= 1) {
    int x = (t >= off) ? s[t - off] : 0;
    __syncthreads();
    s[t] += x;
    __syncthreads();
  }
  if (i < n) {
    row_ptr[i] = partial[blockIdx.x] + s[t] - v;
    dinv[i] = rsqrtf((float)(v + 1));   // +1 self-loop
  }
  if (i == 0) row_ptr[n] = E;
}

// ---------------- CSR scatter (packed {src, w_bits}) ----------------
__global__ void scatter_kernel(const int* __restrict__ rowi, const int* __restrict__ coli,
                               const int* __restrict__ row_ptr, int* __restrict__ fill,
                               const float* __restrict__ dinv,
                               int2* __restrict__ csr_sw, int E) {
  int e = blockIdx.x * 256 + threadIdx.x;
  if (e >= E) return;
  int s = rowi[e], d = coli[e];
  int pos = row_ptr[d] + atomicAdd(&fill[d], 1);
  int2 p;
  p.x = s;
  p.y = __float_as_int(dinv[s] * dinv[d]);
  csr_sw[pos] = p;
}

// ---------------- x f32 -> per-row biased u8 (for agg0 gather) ----------------
__global__ __launch_bounds__(256) void quant_x_kernel(const float* __restrict__ x,
                                                      uint8_t* __restrict__ X8,
                                                      float* __restrict__ xscale) {
  int row = blockIdx.x * 4 + (threadIdx.x >> 6);
  int t = threadIdx.x & 63;
  float4 v = ((const float4*)(x + (size_t)row * FIN))[t];
  float m = fmaxf(fmaxf(fabsf(v.x), fabsf(v.y)), fmaxf(fabsf(v.z), fabsf(v.w)));
  #pragma unroll
  for (int off = 32; off; off >>= 1) m = fmaxf(m, __shfl_xor(m, off, 64));
  float inv = (m > 0.f) ? 127.0f / m : 0.f;
  int q0 = min(127, max(-127, __float2int_rn(v.x * inv))) + 128;
  int q1 = min(127, max(-127, __float2int_rn(v.y * inv))) + 128;
  int q2 = min(127, max(-127, __float2int_rn(v.z * inv))) + 128;
  int q3 = min(127, max(-127, __float2int_rn(v.w * inv))) + 128;
  uint32_t p = ((uint32_t)q0) | ((uint32_t)q1 << 8) |
               ((uint32_t)q2 << 16) | ((uint32_t)q3 << 24);
  ((uint32_t*)X8)[(size_t)row * 64 + t] = p;
  if (t == 0) xscale[row] = (m > 0.f) ? m / 127.0f : 0.f;
}

// ---------------- L0 aggregate-first: AX = A-hat * x (256-d gather) ----------------
__global__ __launch_bounds__(256) void agg0_kernel(
    const uint8_t* __restrict__ X8, const float* __restrict__ xscale,
    const int* __restrict__ row_ptr, const int2* __restrict__ csr_sw,
    const float* __restrict__ dinv,
    int8_t* __restrict__ AX8, float* __restrict__ axscale) {
  const int node = blockIdx.x * 4 + (threadIdx.x >> 6);
  const int t = threadIdx.x & 63;

  float acc[4] = {};
  float sw = 0.f;

  float dn = dinv[node];
  float wself = dn * dn * xscale[node];
  {
    uint32_t d = ((const uint32_t*)X8)[(size_t)node * 64 + t];
    sw += wself;
    acc[0] += wself * (float)(d & 0xffu);
    acc[1] += wself * (float)((d >> 8) & 0xffu);
    acc[2] += wself * (float)((d >> 16) & 0xffu);
    acc[3] += wself * (float)(d >> 24);
  }

  int e = row_ptr[node];
  const int e1 = row_ptr[node + 1];
  for (; e + 4 <= e1; e += 4) {
    int2 p0 = csr_sw[e], p1 = csr_sw[e + 1], p2 = csr_sw[e + 2], p3 = csr_sw[e + 3];
    float w0 = __int_as_float(p0.y) * xscale[p0.x];
    float w1 = __int_as_float(p1.y) * xscale[p1.x];
    float w2 = __int_as_float(p2.y) * xscale[p2.x];
    float w3 = __int_as_float(p3.y) * xscale[p3.x];
    uint32_t d0 = ((const uint32_t*)X8)[(size_t)p0.x * 64 + t];
    uint32_t d1 = ((const uint32_t*)X8)[(size_t)p1.x * 64 + t];
    uint32_t d2 = ((const uint32_t*)X8)[(size_t)p2.x * 64 + t];
    uint32_t d3 = ((const uint32_t*)X8)[(size_t)p3.x * 64 + t];
    sw += w0 + w1 + w2 + w3;
    acc[0] += w0 * (float)(d0 & 0xffu) + w1 * (float)(d1 & 0xffu)
            + w2 * (float)(d2 & 0xffu) + w3 * (float)(d3 & 0xffu);
    acc[1] += w0 * (float)((d0 >> 8) & 0xffu) + w1 * (float)((d1 >> 8) & 0xffu)
            + w2 * (float)((d2 >> 8) & 0xffu) + w3 * (float)((d3 >> 8) & 0xffu);
    acc[2] += w0 * (float)((d0 >> 16) & 0xffu) + w1 * (float)((d1 >> 16) & 0xffu)
            + w2 * (float)((d2 >> 16) & 0xffu) + w3 * (float)((d3 >> 16) & 0xffu);
    acc[3] += w0 * (float)(d0 >> 24) + w1 * (float)(d1 >> 24)
            + w2 * (float)(d2 >> 24) + w3 * (float)(d3 >> 24);
  }
  for (; e < e1; e++) {
    int2 p = csr_sw[e];
    float w = __int_as_float(p.y) * xscale[p.x];
    uint32_t d = ((const uint32_t*)X8)[(size_t)p.x * 64 + t];
    sw += w;
    acc[0] += w * (float)(d & 0xffu);
    acc[1] += w * (float)((d >> 8) & 0xffu);
    acc[2] += w * (float)((d >> 16) & 0xffu);
    acc[3] += w * (float)(d >> 24);
  }

  float c = 128.0f * sw;
  #pragma unroll
  for (int j = 0; j < 4; j++) acc[j] -= c;

  float rm = fmaxf(fmaxf(fabsf(acc[0]), fabsf(acc[1])), fmaxf(fabsf(acc[2]), fabsf(acc[3])));
  #pragma unroll
  for (int off = 32; off; off >>= 1) rm = fmaxf(rm, __shfl_xor(rm, off, 64));
  float qinv = (rm > 0.f) ? 127.0f / rm : 0.f;
  int q0 = min(127, max(-127, __float2int_rn(acc[0] * qinv)));
  int q1 = min(127, max(-127, __float2int_rn(acc[1] * qinv)));
  int q2 = min(127, max(-127, __float2int_rn(acc[2] * qinv)));
  int q3 = min(127, max(-127, __float2int_rn(acc[3] * qinv)));
  uint32_t p = ((uint32_t)(q0 & 0xff)) | ((uint32_t)(q1 & 0xff) << 8) |
               ((uint32_t)(q2 & 0xff) << 16) | ((uint32_t)(q3 & 0xff) << 24);
  ((uint32_t*)AX8)[(size_t)node * 64 + t] = p;
  if (t == 0) axscale[node] = (rm > 0.f) ? rm / 127.0f : 0.f;
}

// ---------------- L0 post-GEMM: dequant + bias + LayerNorm + ReLU + i8 quant ----------------
__global__ __launch_bounds__(256) void ln0_kernel(
    const uint8_t* __restrict__ htu8, const float* __restrict__ scales,
    const float* __restrict__ bias, const float* __restrict__ gamma,
    const float* __restrict__ beta,
    int8_t* __restrict__ hq, float* __restrict__ hscale) {
  const int g = threadIdx.x >> 7;
  const int node = blockIdx.x * 2 + g;
  const int tt = threadIdx.x & 127;
  const int cbL = tt >> 4;
  const int wid = threadIdx.x >> 6;
  __shared__ float red[4];

  float sc = scales[(size_t)node * 8 + cbL];
  uint2 dd = ((const uint2*)(htu8 + (size_t)node * HD))[tt];
  float acc[8];
  acc[0] = sc * ((float)(dd.x & 0xffu) - 128.f);
  acc[1] = sc * ((float)((dd.x >> 8) & 0xffu) - 128.f);
  acc[2] = sc * ((float)((dd.x >> 16) & 0xffu) - 128.f);
  acc[3] = sc * ((float)(dd.x >> 24) - 128.f);
  acc[4] = sc * ((float)(dd.y & 0xffu) - 128.f);
  acc[5] = sc * ((float)((dd.y >> 8) & 0xffu) - 128.f);
  acc[6] = sc * ((float)((dd.y >> 16) & 0xffu) - 128.f);
  acc[7] = sc * ((float)(dd.y >> 24) - 128.f);

  const float4* bias2 = (const float4*)bias;
  float4 ba = bias2[tt * 2], bb = bias2[tt * 2 + 1];
  acc[0] += ba.x; acc[1] += ba.y; acc[2] += ba.z; acc[3] += ba.w;
  acc[4] += bb.x; acc[5] += bb.y; acc[6] += bb.z; acc[7] += bb.w;

  float s = 0.f;
  #pragma unroll
  for (int j = 0; j < 8; j++) s += acc[j];
  #pragma unroll
  for (int off = 32; off; off >>= 1) s += __shfl_down(s, off, 64);
  if ((threadIdx.x & 63) == 0) red[wid] = s;
  __syncthreads();
  float mean = (red[g * 2] + red[g * 2 + 1]) * (1.0f / HD);
  __syncthreads();

  float d[8], s2 = 0.f;
  #pragma unroll
  for (int j = 0; j < 8; j++) { d[j] = acc[j] - mean; s2 += d[j] * d[j]; }
  #pragma unroll
  for (int off = 32; off; off >>= 1) s2 += __shfl_down(s2, off, 64);
  if ((threadIdx.x & 63) == 0) red[wid] = s2;
  __syncthreads();
  float var = (red[g * 2] + red[g * 2 + 1]) * (1.0f / HD);
  float rstd = rsqrtf(var + EPSV);

  const float4* gam2 = (const float4*)gamma;
  const float4* bet2 = (const float4*)beta;
  float4 g0 = gam2[tt * 2], g1 = gam2[tt * 2 + 1];
  float4 be0 = bet2[tt * 2], be1 = bet2[tt * 2 + 1];
  float gv[8] = {g0.x, g0.y, g0.z, g0.w, g1.x, g1.y, g1.z, g1.w};
  float bv[8] = {be0.x, be0.y, be0.z, be0.w, be1.x, be1.y, be1.z, be1.w};
  float o[8];
  float rmax = 0.f;
  #pragma unroll
  for (int j = 0; j < 8; j++) {
    o[j] = fmaxf(d[j] * rstd * gv[j] + bv[j], 0.0f);
    rmax = fmaxf(rmax, o[j]);
  }

  __syncthreads();
  #pragma unroll
  for (int off = 32; off; off >>= 1) rmax = fmaxf(rmax, __shfl_xor(rmax, off, 64));
  if ((threadIdx.x & 63) == 0) red[wid] = rmax;
  __syncthreads();
  float rm = fmaxf(red[g * 2], red[g * 2 + 1]);
  float qinv = (rm > 0.f) ? 127.0f / rm : 0.f;
  int q[8];
  #pragma unroll
  for (int j = 0; j < 8; j++) q[j] = min(127, __float2int_rn(o[j] * qinv));
  uint32_t p0 = ((uint32_t)q[0]) | ((uint32_t)q[1] << 8) | ((uint32_t)q[2] << 16) | ((uint32_t)q[3] << 24);
  uint32_t p1 = ((uint32_t)q[4]) | ((uint32_t)q[5] << 8) | ((uint32_t)q[6] << 16) | ((uint32_t)q[7] << 24);
  uint2 pk; pk.x = p0; pk.y = p1;
  ((uint2*)(hq + (size_t)node * HD))[tt] = pk;
  if (tt == 0) hscale[node] = (rm > 0.f) ? rm / 127.0f : 0.f;
}

// ---------------- batched weight prep (all 4 layers, hoisted) ----------------
__device__ __forceinline__ const float* layer_W(const float* W0, const float* Ws, int L) {
  return (L == 0) ? W0 : Ws + (size_t)(L - 1) * HD * HD;
}

__global__ void wamax_full_kernel(const float* __restrict__ W0, const float* __restrict__ Ws,
                                  float* __restrict__ colmaxf, float* __restrict__ wscale) {
  __shared__ float lds[8][32];
  int L = blockIdx.y;
  int K = (L == 0) ? FIN : HD;
  const float* W = layer_W(W0, Ws, L);
  int n = blockIdx.x * 32 + threadIdx.x;
  float m = 0.f;
  for (int k = threadIdx.y; k < K; k += 8)
    m = fmaxf(m, fabsf(W[(size_t)k * HD + n]));
  lds[threadIdx.y][threadIdx.x] = m;
  __syncthreads();
  if (threadIdx.y == 0) {
    #pragma unroll
    for (int i = 1; i < 8; i++) m = fmaxf(m, lds[i][threadIdx.x]);
    colmaxf[L * HD + n] = m;
    wscale[L * HD + n] = (m > 0.f) ? m / 127.0f : 0.f;
  }
}

// Wt8_all layout: L0 at off 0 (HD rows x 256), L1.. at FIN*HD + (L-1)*HD*HD
__global__ void transpose_wq8_all_kernel(const float* __restrict__ W0,
                                         const float* __restrict__ Ws,
                                         const float* __restrict__ colmaxf,
                                         int8_t* __restrict__ Wt8_all) {
  __shared__ float tile[32][33];
  int L = blockIdx.z;
  int K = (L == 0) ? FIN : HD;
  int k0 = blockIdx.y * 32;
  if (k0 >= K) return;
  const float* W = layer_W(W0, Ws, L);
  int8_t* Wt8 = Wt8_all + ((L == 0) ? 0 : (size_t)FIN * HD + (size_t)(L - 1) * HD * HD);
  int n0 = blockIdx.x * 32;
  int tx = threadIdx.x, ty = threadIdx.y;  // 32 x 8
  #pragma unroll
  for (int i = ty; i < 32; i += 8) tile[i][tx] = W[(size_t)(k0 + i) * HD + n0 + tx];
  __syncthreads();
  #pragma unroll
  for (int i = ty; i < 32; i += 8) {
    float cm = colmaxf[L * HD + n0 + i];
    float inv = (cm > 0.f) ? 127.0f / cm : 0.f;
    int q = min(127, max(-127, __float2int_rn(tile[tx][i] * inv)));
    Wt8[(size_t)(n0 + i) * K + k0 + tx] = (int8_t)q;
  }
}

// ---------------- i8 MFMA GEMM + fused u8-quant epilogue ----------------
__global__ __launch_bounds__(256, 4) void gemm_i8_q8_kernel(
    const int8_t* __restrict__ A8, const float* __restrict__ hscale,
    const int8_t* __restrict__ Wt8, const float* __restrict__ wscale,
    uint8_t* __restrict__ C8, float* __restrict__ scales, int M, int K) {
  __shared__ __align__(16) int8_t As[2][128 * 64];
  __shared__ __align__(16) int8_t Bs[2][128 * 64];
  __shared__ float smax[2][128];
  const int tid = threadIdx.x;
  const int w = tid >> 6, l = tid & 63;

  const int nwg = gridDim.x;            // nmt*8, divisible by 8
  const int o = blockIdx.x;
  const int lid = (o & 7) * (nwg >> 3) + (o >> 3);
  const int m0 = (lid >> 3) * 128, n0 = (lid & 7) * 128;
  const int cb = lid & 7;               // col-block id
  const int wr = w >> 1, wc = w & 1;    // 2x2 wave grid, each wave 64x64

  i32x4 acc[4][4] = {};

  const int r0 = tid >> 2;              // 0..63
  const int c16 = (tid & 3) * 16;       // byte offset within BK=64 row
  int ar0 = m0 + r0;       if (ar0 >= M) ar0 = M - 1;
  int ar1 = m0 + r0 + 64;  if (ar1 >= M) ar1 = M - 1;
  const int8_t* a0 = A8 + (size_t)ar0 * K + c16;
  const int8_t* a1 = A8 + (size_t)ar1 * K + c16;
  const int8_t* b0 = Wt8 + (size_t)(n0 + r0) * K + c16;
  const int8_t* b1 = Wt8 + (size_t)(n0 + r0 + 64) * K + c16;

  const int mrow = l & 15;
  const int kch = (l >> 4) * 16;        // byte offset within row

  auto stage = [&](int b, int k) {
    int8_t* asw = &As[b][w * 1024];
    int8_t* bsw = &Bs[b][w * 1024];
    load_g2l_16(a0 + k, asw);
    load_g2l_16(a1 + k, asw + 4096);
    load_g2l_16(b0 + k, bsw);
    load_g2l_16(b1 + k, bsw + 4096);
  };

  const int nit = K >> 6;
  stage(0, 0);
  __syncthreads();

  int cur = 0;
  for (int t = 0; t < nit; ++t) {
    if (t + 1 < nit) stage(cur ^ 1, (t + 1) << 6);
    i32x4 af[4], bf_[4];
    #pragma unroll
    for (int m = 0; m < 4; m++)
      af[m] = *(const i32x4*)&As[cur][(wr * 64 + m * 16 + mrow) * 64 + kch];
    #pragma unroll
    for (int n = 0; n < 4; n++)
      bf_[n] = *(const i32x4*)&Bs[cur][(wc * 64 + n * 16 + mrow) * 64 + kch];
    #pragma unroll
    for (int m = 0; m < 4; m++)
      #pragma unroll
      for (int n = 0; n < 4; n++)
        acc[m][n] = __builtin_amdgcn_mfma_i32_16x16x64_i8(af[m], bf_[n], acc[m][n], 0, 0, 0);
    __syncthreads();
    cur ^= 1;
  }

  // ---- epilogue: per-row amax over this block's 128 cols, then quant ----
  float wsv[4];
  #pragma unroll
  for (int n = 0; n < 4; n++) wsv[n] = wscale[n0 + wc * 64 + n * 16 + (l & 15)];

  #pragma unroll
  for (int m = 0; m < 4; m++) {
    #pragma unroll
    for (int r = 0; r < 4; r++) {
      int rl = wr * 64 + m * 16 + (l >> 4) * 4 + r;
      int grow = m0 + rl; if (grow >= M) grow = M - 1;
      float v = 0.f;
      #pragma unroll
      for (int n = 0; n < 4; n++)
        v = fmaxf(v, fabsf((float)acc[m][n][r] * wsv[n]));
      v *= hscale[grow];   // hs >= 0: factor out of the max
      #pragma unroll
      for (int mask = 1; mask < 16; mask <<= 1) v = fmaxf(v, __shfl_xor(v, mask, 64));
      if ((l & 15) == 0) smax[wc][rl] = v;
    }
  }
  __syncthreads();

  #pragma unroll
  for (int m = 0; m < 4; m++) {
    #pragma unroll
    for (int r = 0; r < 4; r++) {
      int rl = wr * 64 + m * 16 + (l >> 4) * 4 + r;
      int grow = m0 + rl;
      float mx = fmaxf(smax[0][rl], smax[1][rl]);
      float inv = (mx > 0.f) ? 127.0f / mx : 0.f;
      if (grow < M) {
        float hs = hscale[grow];
        if (wc == 0 && (l & 15) == 0)
          scales[(size_t)grow * 8 + cb] = (mx > 0.f) ? mx / 127.0f : 0.f;
        #pragma unroll
        for (int n = 0; n < 4; n++) {
          int gcol = n0 + wc * 64 + n * 16 + (l & 15);
          int u = __float2int_rn((float)acc[m][n][r] * hs * wsv[n] * inv) + 128;
          C8[(size_t)grow * HD + gcol] = (uint8_t)u;
        }
      }
    }
  }
}

// ---------------- fused aggregate + bias + LayerNorm + ReLU (u8 gather, i8 out) ----------------
// ONE 64-lane wave per node; lane covers 16 cols via one uint4 (16B) load.
// No LDS, no barriers: all reductions are 64-lane shuffles.
__global__ __launch_bounds__(256) void agg_ln_u8_kernel(
    const uint8_t* __restrict__ htu8, const float* __restrict__ scales,
    const int* __restrict__ row_ptr, const int2* __restrict__ csr_sw,
    const float* __restrict__ dinv, const float* __restrict__ bias,
    const float* __restrict__ gamma, const float* __restrict__ beta,
    int8_t* __restrict__ hq, float* __restrict__ hscale) {
  const int node = blockIdx.x * 4 + (threadIdx.x >> 6);
  const int l = threadIdx.x & 63;
  const int cbL = l >> 3;            // col-block of cols [l*16, l*16+16)

  float acc[16] = {};
  float sw = 0.f;

  auto ACC = [&](float w, const uint4& dd) {
    sw += w;
    const uint32_t dw[4] = {dd.x, dd.y, dd.z, dd.w};
    #pragma unroll
    for (int c = 0; c < 4; c++) {
      acc[4 * c + 0] += w * (float)(dw[c] & 0xffu);
      acc[4 * c + 1] += w * (float)((dw[c] >> 8) & 0xffu);
      acc[4 * c + 2] += w * (float)((dw[c] >> 16) & 0xffu);
      acc[4 * c + 3] += w * (float)(dw[c] >> 24);
    }
  };

  // self-loop
  float dn = dinv[node];
  float wself = dn * dn * scales[(size_t)node * 8 + cbL];
  ACC(wself, ((const uint4*)(htu8 + (size_t)node * HD))[l]);

  int e = row_ptr[node];
  const int e1 = row_ptr[node + 1];
  for (; e + 4 <= e1; e += 4) {
    int2 p0 = csr_sw[e], p1 = csr_sw[e + 1], p2 = csr_sw[e + 2], p3 = csr_sw[e + 3];
    float w0 = __int_as_float(p0.y) * scales[(size_t)p0.x * 8 + cbL];
    float w1 = __int_as_float(p1.y) * scales[(size_t)p1.x * 8 + cbL];
    float w2 = __int_as_float(p2.y) * scales[(size_t)p2.x * 8 + cbL];
    float w3 = __int_as_float(p3.y) * scales[(size_t)p3.x * 8 + cbL];
    uint4 d0 = ((const uint4*)(htu8 + (size_t)p0.x * HD))[l];
    uint4 d1 = ((const uint4*)(htu8 + (size_t)p1.x * HD))[l];
    uint4 d2 = ((const uint4*)(htu8 + (size_t)p2.x * HD))[l];
    uint4 d3 = ((const uint4*)(htu8 + (size_t)p3.x * HD))[l];
    ACC(w0, d0);
    ACC(w1, d1);
    ACC(w2, d2);
    ACC(w3, d3);
  }
  for (; e < e1; e++) {
    int2 p = csr_sw[e];
    float wgt = __int_as_float(p.y) * scales[(size_t)p.x * 8 + cbL];
    ACC(wgt, ((const uint4*)(htu8 + (size_t)p.x * HD))[l]);
  }

  // +128-bias correction and layer bias (cols l*16 .. l*16+15)
  const float4* bias4 = (const float4*)bias;
  float c128 = 128.0f * sw;
  #pragma unroll
  for (int c = 0; c < 4; c++) {
    float4 bb = bias4[l * 4 + c];
    acc[4 * c + 0] += bb.x - c128;
    acc[4 * c + 1] += bb.y - c128;
    acc[4 * c + 2] += bb.z - c128;
    acc[4 * c + 3] += bb.w - c128;
  }

  // mean / var over the full 1024-col row: 64-lane shuffle reductions
  float s = 0.f;
  #pragma unroll
  for (int j = 0; j < 16; j++) s += acc[j];
  #pragma unroll
  for (int off = 32; off; off >>= 1) s += __shfl_xor(s, off, 64);
  float mean = s * (1.0f / HD);

  float d[16], s2 = 0.f;
  #pragma unroll
  for (int j = 0; j < 16; j++) { d[j] = acc[j] - mean; s2 += d[j] * d[j]; }
  #pragma unroll
  for (int off = 32; off; off >>= 1) s2 += __shfl_xor(s2, off, 64);
  float rstd = rsqrtf(s2 * (1.0f / HD) + EPSV);

  const float4* gam4 = (const float4*)gamma;
  const float4* bet4 = (const float4*)beta;
  float o[16];
  float rmax = 0.f;
  #pragma unroll
  for (int c = 0; c < 4; c++) {
    float4 gg = gam4[l * 4 + c];
    float4 be = bet4[l * 4 + c];
    float gv[4] = {gg.x, gg.y, gg.z, gg.w};
    float bv[4] = {be.x, be.y, be.z, be.w};
    #pragma unroll
    for (int j = 0; j < 4; j++) {
      float v = fmaxf(d[4 * c + j] * rstd * gv[j] + bv[j], 0.0f);
      o[4 * c + j] = v;
      rmax = fmaxf(rmax, v);
    }
  }
  #pragma unroll
  for (int off = 32; off; off >>= 1) rmax = fmaxf(rmax, __shfl_xor(rmax, off, 64));
  float qinv = (rmax > 0.f) ? 127.0f / rmax : 0.f;

  uint32_t pw[4];
  #pragma unroll
  for (int c = 0; c < 4; c++) {
    int q0 = min(127, __float2int_rn(o[4 * c + 0] * qinv));
    int q1 = min(127, __float2int_rn(o[4 * c + 1] * qinv));
    int q2 = min(127, __float2int_rn(o[4 * c + 2] * qinv));
    int q3 = min(127, __float2int_rn(o[4 * c + 3] * qinv));
    pw[c] = ((uint32_t)q0) | ((uint32_t)q1 << 8) | ((uint32_t)q2 << 16) | ((uint32_t)q3 << 24);
  }
  uint4 pk; pk.x = pw[0]; pk.y = pw[1]; pk.z = pw[2]; pk.w = pw[3];
  ((uint4*)(hq + (size_t)node * HD))[l] = pk;
  if (l == 0) hscale[node] = (rmax > 0.f) ? rmax / 127.0f : 0.f;
}

// ---------------- graph boundaries (batch is sorted) ----------------
__global__ void starts_kernel(const int* __restrict__ batch, int* __restrict__ start,
                              int n, int ngraph) {
  int g = blockIdx.x * blockDim.x + threadIdx.x;
  if (g > ngraph) return;
  int lo = 0, hi = n;
  while (lo < hi) {
    int mid = (lo + hi) >> 1;
    if (batch[mid] < g) lo = mid + 1; else hi = mid;
  }
  start[g] = lo;
}

// ---------------- mean-pool per graph (i8 input): partial sums + atomics ----------------
#define POOL_CHUNKS 8
__global__ void pool_partial_kernel(const int8_t* __restrict__ hq,
                                    const float* __restrict__ hscale,
                                    const int* __restrict__ start,
                                    float* __restrict__ out) {
  int g = blockIdx.y, c = blockIdx.x;
  int t = threadIdx.x;
  int s0 = start[g], s1 = start[g + 1];
  int len = s1 - s0;
  int per = (len + POOL_CHUNKS - 1) / POOL_CHUNKS;
  int a = s0 + c * per;
  int b = min(a + per, s1);
  if (a >= b) return;
  f32x4 acc = {0.f, 0.f, 0.f, 0.f};
  for (int n = a; n < b; n++) {
    float hs = hscale[n];
    uint32_t d = ((const uint32_t*)(hq + (size_t)n * HD))[t];   // 4 vals, 0..127
    acc[0] += hs * (float)(d & 0xffu);
    acc[1] += hs * (float)((d >> 8) & 0xffu);
    acc[2] += hs * (float)((d >> 16) & 0xffu);
    acc[3] += hs * (float)(d >> 24);
  }
  float* o = out + (size_t)g * HD + t * 4;
  atomicAdd(o + 0, acc[0]);
  atomicAdd(o + 1, acc[1]);
  atomicAdd(o + 2, acc[2]);
  atomicAdd(o + 3, acc[3]);
}

__global__ void pool_div_kernel(float* __restrict__ out, const int* __restrict__ start) {
  int i = blockIdx.x * 256 + threadIdx.x;
  if (i >= NG * HD) return;
  int g = i >> 10;
  float c = (float)max(start[g + 1] - start[g], 1);
  out[i] = out[i] / c;
}

extern "C" void kernel_launch(void* const* d_in, const int* in_sizes, int n_in,
                              void* d_out, int out_size, void* d_ws, size_t ws_size,
                              hipStream_t stream) {
  const float* x      = (const float*)d_in[0];
  const int*   eidx   = (const int*)d_in[1];
  const int*   batch  = (const int*)d_in[2];
  const float* W0     = (const float*)d_in[3];
  const float* b0     = (const float*)d_in[4];
  const float* Ws     = (const float*)d_in[5];
  const float* bs     = (const float*)d_in[6];
  const float* gammas = (const float*)d_in[7];
  const float* betas  = (const float*)d_in[8];
  float* out = (float*)d_out;

  const int* erow = eidx;        // sources
  const int* ecol = eidx + NE;   // targets (aggregation index)

  char* ws = (char*)d_ws;
  size_t off = 0;
  auto alloc = [&](size_t bytes) {
    void* p = ws + off;
    off = (off + bytes + 255) & ~(size_t)255;
    return p;
  };
  int*     cnt     = (int*)alloc((size_t)NN * 4);      // later: wscale[4K] + colmaxf[4K]
  int*     row_ptr = (int*)alloc((size_t)(NN + 1) * 4);
  int*     fill    = (int*)alloc((size_t)NN * 4);      // later: hscale (NN floats)
  int*     partial = (int*)alloc(256 * 4);
  float*   dinv    = (float*)alloc((size_t)NN * 4);
  int2*    csr_sw  = (int2*)alloc((size_t)NE * 8);
  int8_t*  Wt8     = (int8_t*)alloc((size_t)FIN * HD + 3 * (size_t)HD * HD);
  int8_t*  A8      = (int8_t*)alloc((size_t)NN * HD);  // i8 activations (pitch 1024)
  uint8_t* ht8     = (uint8_t*)alloc((size_t)NN * HD); // u8 GEMM output
  float*   scales  = (float*)alloc((size_t)NN * 8 * 4);
  uint8_t* X8      = (uint8_t*)alloc((size_t)NN * FIN); // biased-u8 x (L0 gather)
  int8_t*  AX8     = (int8_t*)alloc((size_t)NN * FIN);  // i8 aggregated x (GEMM0 input)
  float*   xscale  = (float*)alloc((size_t)NN * 4);
  float*   axscale = (float*)alloc((size_t)NN * 4);
  int*     gstart  = (int*)alloc(65 * 4);

  float* wscale  = (float*)cnt;                 // cnt dead after scans
  float* colmaxf = (float*)cnt + 4096;
  float* hscale  = (float*)fill;                // fill dead after scatter

  hipMemsetAsync(cnt, 0, (size_t)NN * 4, stream);
  hipMemsetAsync(fill, 0, (size_t)NN * 4, stream);
  hipMemsetAsync(out, 0, (size_t)NG * HD * 4, stream);

  hist_kernel<<<(NE + 255) / 256, 256, 0, stream>>>(ecol, cnt, NE);
  int nb = (NN + 255) / 256;  // 196
  scan_partial_kernel<<<nb, 256, 0, stream>>>(cnt, partial, NN);
  scan_scan_kernel<<<1, 256, 0, stream>>>(partial, nb);
  scan_final_kernel<<<nb, 256, 0, stream>>>(cnt, partial, row_ptr, dinv, NN, NE);
  scatter_kernel<<<(NE + 255) / 256, 256, 0, stream>>>(erow, ecol, row_ptr, fill, dinv,
                                                       csr_sw, NE);
  starts_kernel<<<1, 128, 0, stream>>>(batch, gstart, NN, NG);

  // x -> biased u8 (for agg0's gather)
  quant_x_kernel<<<NN / 4, 256, 0, stream>>>(x, X8, xscale);

  // batched weight prep for all 4 layers (cnt region dead after scans)
  wamax_full_kernel<<<dim3(HD / 32, 4), dim3(32, 8), 0, stream>>>(W0, Ws, colmaxf, wscale);
  transpose_wq8_all_kernel<<<dim3(HD / 32, HD / 32, 4), dim3(32, 8), 0, stream>>>(
      W0, Ws, colmaxf, Wt8);

  const int nmt = (NN + 127) / 128;  // 391 m-tiles

  // ---- L0: aggregate-first (A-hat x is a 256-d gather: 4x fewer bytes) ----
  agg0_kernel<<<NN / 4, 256, 0, stream>>>(X8, xscale, row_ptr, csr_sw, dinv, AX8, axscale);
  gemm_i8_q8_kernel<<<nmt * 8, 256, 0, stream>>>(AX8, axscale, Wt8, wscale,
                                                 ht8, scales, NN, FIN);
  ln0_kernel<<<NN / 2, 256, 0, stream>>>(ht8, scales, b0, gammas, betas, A8, hscale);

  // ---- L1-3: GEMM then fused aggregate+LN ----
  for (int L = 1; L < 4; L++) {
    const int8_t* WtL = Wt8 + (size_t)FIN * HD + (size_t)(L - 1) * HD * HD;
    const float* bias = bs + (size_t)(L - 1) * HD;
    gemm_i8_q8_kernel<<<nmt * 8, 256, 0, stream>>>(A8, hscale, WtL, wscale + L * HD,
                                                   ht8, scales, NN, HD);
    agg_ln_u8_kernel<<<NN / 4, 256, 0, stream>>>(ht8, scales, row_ptr, csr_sw,
                                                 dinv, bias, gammas + (size_t)L * HD,
                                                 betas + (size_t)L * HD, A8, hscale);
  }

  pool_partial_kernel<<<dim3(POOL_CHUNKS, NG), 256, 0, stream>>>(A8, hscale, gstart, out);
  pool_div_kernel<<<(NG * HD + 255) / 256, 256, 0, stream>>>(out, gstart);
}